// Round 22
// baseline (143.399 us; speedup 1.0000x reference)
//
#include <hip/hip_runtime.h>
#include <hip/hip_bf16.h>

// MultiHeadBatchedMixers, group-sorted two-kernel structure (no atomics):
//   prepack+sort (LDS-staged transpose, 4-BAND BATCHED): per block-pass, stage 4
//       16-row bands: all stage-1 linear reads issued together (4x MLP), one
//       barrier, 4 linear write-outs, one barrier. Both global sides coalesced.
//   Kernel A (grid 1536x256, XCD-chunked, group-ordered): H = GELU(W1c@X@W1t^T+B1)
//   Kernel B (grid 768x256, XCD-chunked, group-ordered): 4 waves = 2k x 2wq,
//       64c x 64n per wave; LDS combine; plain f32 stores
// bf16 MFMA 16x16x32, f32 accumulate. Fragment-packed ws layout [tile][ks][lane][8].
// NOTE (R8/R10): VGPR+AGPR share one file; never min-waves-bound MFMA kernels.
// NOTE (R12-R14): cost tracks load instructions & intensity; 64x64 tiles optimal.
// NOTE (R15/R17): acc-lifetime splits and manual double-buffering are no-ops.
// NOTE (R18-R21): the binding resource is MEMORY SEGMENTS per instruction; after
// both sides are coalesced, the next limiter is per-band barrier serialization.

namespace {
constexpr int NHEAD = 12, NTOK = 256, HDIM = 64, HIDD = 512, NBATCH = 32, TOPK = 2;
constexpr int NCHAIN = NBATCH * NHEAD * TOPK;  // 768
constexpr int NBH = NBATCH * NHEAD;            // 384
constexpr int NGROUP = 8 * NHEAD;              // 96

// Kernel A LDS: per-wave T1^T [64 e][64 d] bf16, pitch +16B
constexpr int P_T1 = HDIM * 2 + 16;   // 144
constexpr int T1_W = 64 * P_T1;       // 9216
constexpr int SMA_TOTAL = 4 * T1_W;   // 36864
// Kernel B LDS: per-wave T3^T [64 n][64 c] (4 waves); combine aliases [0,32768)
constexpr int P_T3 = HDIM * 2 + 16;   // 144
constexpr int T3_W = 64 * P_T3;       // 9216
constexpr int SMB_TOTAL = 4 * T3_W;   // 36864

// ws element layout (bf16 shorts): [H][w1t][w2t][x][b1][b2][w1c][w2c], then orders
constexpr size_t SZ_H    = (size_t)NCHAIN * HDIM * HIDD;          // 25,165,824
constexpr size_t OFF_H   = 0;
constexpr size_t OFF_W1T = OFF_H + SZ_H;
constexpr size_t SZ_W1T  = (size_t)8 * NHEAD * HIDD * NTOK;       // 12,582,912
constexpr size_t OFF_W2T = OFF_W1T + SZ_W1T;
constexpr size_t SZ_W2T  = (size_t)8 * NHEAD * NTOK * HIDD;
constexpr size_t OFF_X   = OFF_W2T + SZ_W2T;
constexpr size_t SZ_X    = (size_t)NBATCH * NHEAD * HDIM * NTOK;  // 6,291,456
constexpr size_t OFF_B1  = OFF_X + SZ_X;
constexpr size_t SZ_B1   = (size_t)8 * NHEAD * HDIM * HIDD;
constexpr size_t OFF_B2  = OFF_B1 + SZ_B1;
constexpr size_t SZ_B2   = (size_t)8 * NHEAD * HDIM * NTOK;
constexpr size_t OFF_W1C = OFF_B2 + SZ_B2;
constexpr size_t SZ_W1C  = (size_t)8 * NHEAD * HDIM * HDIM;       // 393,216
constexpr size_t OFF_W2C = OFF_W1C + SZ_W1C;
constexpr size_t SZ_W2C  = (size_t)8 * NHEAD * HDIM * HDIM;
constexpr size_t TOTEL   = OFF_W2C + SZ_W2C;                      // shorts
constexpr size_t NEED    = TOTEL * 2 + (NCHAIN + NBH) * 4;

// prepack band counts (band = 16 rows x R cols, contiguous on both sides)
constexpr int NB_W1T = (int)(SZ_W1T / (16 * 256));  // 3072
constexpr int NB_W2T = (int)(SZ_W2T / (16 * 512));  // 1536
constexpr int NB_X   = (int)(SZ_X   / (16 * 256));  // 1536
constexpr int NB_W1C = (int)(SZ_W1C / (16 * 64));   // 384
constexpr int NB_W2C = (int)(SZ_W2C / (16 * 64));   // 384
constexpr int NB_B1  = (int)(SZ_B1  / (16 * 512));  // 384
constexpr int NB_B2  = (int)(SZ_B2  / (16 * 256));  // 384
constexpr int NB_TOT = NB_W1T + NB_W2T + NB_X + NB_W1C + NB_W2C + NB_B1 + NB_B2;  // 7680
}

typedef float f32x4 __attribute__((ext_vector_type(4)));
typedef short bf16x8 __attribute__((ext_vector_type(8)));
typedef short bf16x4 __attribute__((ext_vector_type(4)));

#define MFMA16(a, b, c) __builtin_amdgcn_mfma_f32_16x16x32_bf16((a), (b), (c), 0, 0, 0)

__device__ __forceinline__ short f2bf(float f) {
  union { float f; unsigned u; } v; v.f = f;
  unsigned r = v.u + 0x7fffu + ((v.u >> 16) & 1u);
  return (short)(r >> 16);
}

__device__ __forceinline__ bf16x8 ld_gfrag(const float* p) {
  float4 a = *(const float4*)p;
  float4 b = *(const float4*)(p + 4);
  bf16x8 r;
  r[0] = f2bf(a.x); r[1] = f2bf(a.y); r[2] = f2bf(a.z); r[3] = f2bf(a.w);
  r[4] = f2bf(b.x); r[5] = f2bf(b.y); r[6] = f2bf(b.z); r[7] = f2bf(b.w);
  return r;
}

__device__ __forceinline__ f32x4 bf4f(bf16x4 v) {
  f32x4 r;
  #pragma unroll
  for (int i = 0; i < 4; ++i) {
    union { unsigned u; float f; } t;
    t.u = ((unsigned)(unsigned short)v[i]) << 16;
    r[i] = t.f;
  }
  return r;
}

// gelu(x) = x * rcp(1 + exp2(-2.30220826 * x * (1 + 0.044715 x^2)))  [err ~1e-7 << bf16]
__device__ __forceinline__ float gelu_fast(float x) {
  float arg = -2.30220826f * x * __builtin_fmaf(0.044715f, x * x, 1.0f);
  float e = __builtin_amdgcn_exp2f(arg);
  return x * __builtin_amdgcn_rcpf(1.0f + e);
}

// XCD-chunk swizzle (nwg % 8 == 0): logical sequence contiguous per XCD.
__device__ __forceinline__ int xcd_chunk(int bx, int nwg) {
  return (bx & 7) * (nwg >> 3) + (bx >> 3);
}

// LDS swizzles (bank-spread, self-inverse XOR within 128-chunk groups)
__device__ __forceinline__ int swz16(int c) { return c ^ ((c >> 4) & 7); }         // 16B chunks
__device__ __forceinline__ int swz8(int c)  { return c ^ (((c >> 4) & 3) << 1); }  // 8B chunks

// ---------------- Prepack (+ block-0 group sort), 4-band batched LDS transpose ----------------
__global__ __launch_bounds__(256) void prepack_sort_kernel(
    const float* __restrict__ w1t, const float* __restrict__ w2t,
    const float* __restrict__ x, const float* __restrict__ w1c,
    const float* __restrict__ w2c, const float* __restrict__ b1,
    const float* __restrict__ b2, short* __restrict__ wsb,
    const int* __restrict__ eidx, int* __restrict__ order, int* __restrict__ order2) {
  if (blockIdx.x == 0) {
    __shared__ int keys[NCHAIN];
    __shared__ int keys2[NBH];
    __shared__ int cnt[NGROUP + 1];
    __shared__ int cnt2[NGROUP + 1];
    const int t = threadIdx.x;
    for (int i = t; i <= NGROUP; i += 256) { cnt[i] = 0; cnt2[i] = 0; }
    __syncthreads();
    for (int i = t; i < NCHAIN; i += 256) {
      int h = (i >> 1) % NHEAD;
      int key = eidx[i] * NHEAD + h;
      keys[i] = key;
      atomicAdd(&cnt[key + 1], 1);
    }
    for (int i = t; i < NBH; i += 256) {
      int h = i % NHEAD;
      int key = eidx[i * TOPK] * NHEAD + h;
      keys2[i] = key;
      atomicAdd(&cnt2[key + 1], 1);
    }
    __syncthreads();
    if (t == 0) for (int i = 1; i <= NGROUP; ++i) cnt[i] += cnt[i - 1];
    if (t == 1) for (int i = 1; i <= NGROUP; ++i) cnt2[i] += cnt2[i - 1];
    __syncthreads();
    for (int i = t; i < NCHAIN; i += 256) {
      int pos = atomicAdd(&cnt[keys[i]], 1);  // rank within group (order-agnostic downstream)
      order[pos] = i;
    }
    for (int i = t; i < NBH; i += 256) {
      int pos = atomicAdd(&cnt2[keys2[i]], 1);
      order2[pos] = i;
    }
    __syncthreads();
  }

  __shared__ __align__(16) short tile[4][8192];  // 4 x 16KB band tiles

  // grid = 1920, 4 bands per block: bands [bx*4, bx*4+4)
  const int b0 = blockIdx.x * 4;

  // stage 1 (all 4 bands): linear read + convert + permuted (swizzled) LDS store
  #pragma unroll 1
  for (int j = 0; j < 4; ++j) {
    const int band = b0 + j;
    const float* s; int R; bool g8;
    int bb = band;
    if (bb < NB_W1T)                 { s = w1t; R = 256; g8 = true; }
    else if ((bb -= NB_W1T) < NB_W2T){ s = w2t; R = 512; g8 = true; }
    else if ((bb -= NB_W2T) < NB_X)  { s = x;   R = 256; g8 = true; }
    else if ((bb -= NB_X) < NB_W1C)  { s = w1c; R = 64;  g8 = true; }
    else if ((bb -= NB_W1C) < NB_W2C){ s = w2c; R = 64;  g8 = true; }
    else if ((bb -= NB_W2C) < NB_B1) { s = b1;  R = 512; g8 = false; }
    else                             { bb -= NB_B1; s = b2; R = 256; g8 = false; }
    const size_t eloff = (size_t)bb * 16 * R;
    const int n8 = (16 * R) / 8;
    if (g8) {
      for (int l8 = threadIdx.x; l8 < n8; l8 += 256) {
        const int l = l8 * 8;
        const int r = l / R, c8 = (l % R) >> 3;
        const int chunk = (c8 >> 2) * 64 + (c8 & 3) * 16 + r;
        *(bf16x8*)(tile[j] + swz16(chunk) * 8) = ld_gfrag(s + eloff + l);
      }
    } else {
      for (int l8 = threadIdx.x; l8 < n8; l8 += 256) {
        const int l = l8 * 8;
        const int r = l / R, c = l % R;
        bf16x8 v = ld_gfrag(s + eloff + l);
        #pragma unroll
        for (int q = 0; q < 2; ++q) {
          const int e4 = (c >> 2) + q;
          const int chunk = (e4 >> 2) * 64 + (e4 & 3) * 16 + r;
          bf16x4 p;
          #pragma unroll
          for (int i = 0; i < 4; ++i) p[i] = v[q * 4 + i];
          *(bf16x4*)(tile[j] + swz8(chunk) * 4) = p;
        }
      }
    }
  }
  __syncthreads();

  // stage 2 (all 4 bands): swizzled LDS read + linear global write
  #pragma unroll 1
  for (int j = 0; j < 4; ++j) {
    const int band = b0 + j;
    size_t dbase; int R; bool g8;
    int bb = band;
    if (bb < NB_W1T)                 { dbase = OFF_W1T; R = 256; g8 = true; }
    else if ((bb -= NB_W1T) < NB_W2T){ dbase = OFF_W2T; R = 512; g8 = true; }
    else if ((bb -= NB_W2T) < NB_X)  { dbase = OFF_X;   R = 256; g8 = true; }
    else if ((bb -= NB_X) < NB_W1C)  { dbase = OFF_W1C; R = 64;  g8 = true; }
    else if ((bb -= NB_W1C) < NB_W2C){ dbase = OFF_W2C; R = 64;  g8 = true; }
    else if ((bb -= NB_W2C) < NB_B1) { dbase = OFF_B1;  R = 512; g8 = false; }
    else                             { bb -= NB_B1; dbase = OFF_B2; R = 256; g8 = false; }
    const size_t eloff = (size_t)bb * 16 * R;
    const int n8 = (16 * R) / 8;
    if (g8) {
      for (int l8 = threadIdx.x; l8 < n8; l8 += 256)
        *(bf16x8*)(wsb + dbase + eloff + (size_t)l8 * 8) =
            *(const bf16x8*)(tile[j] + swz16(l8) * 8);
    } else {
      for (int l8 = threadIdx.x; l8 < n8; l8 += 256) {
        const int l4 = l8 * 2;
        bf16x8 v;
        bf16x4 a = *(const bf16x4*)(tile[j] + swz8(l4) * 4);
        bf16x4 b = *(const bf16x4*)(tile[j] + swz8(l4 + 1) * 4);
        #pragma unroll
        for (int i = 0; i < 4; ++i) { v[i] = a[i]; v[4 + i] = b[i]; }
        *(bf16x8*)(wsb + dbase + eloff + (size_t)l8 * 8) = v;
      }
    }
  }
}

// ---------------- Kernel A (64 e per wave; fragment-packed loads/stores) ----------------
// grid = 768*2. L = xcd_chunk(bx,1536): sid = L>>1 -> chain = order[sid], eblk = L&1.
template <bool PP>
__global__ __launch_bounds__(256) void mixer_h_kernel(
    const float* __restrict__ x, const int* __restrict__ eidx,
    const float* __restrict__ w1t, const float* __restrict__ w1c, const float* __restrict__ b1,
    const short* __restrict__ wsb, const int* __restrict__ order, short* __restrict__ hws) {
  __shared__ __align__(16) char smem[SMA_TOTAL];
  const int L = xcd_chunk(blockIdx.x, NCHAIN * 2);
  const int sid = L >> 1, eblk = L & 1;
  const int bhk = PP ? order[sid] : sid;
  const int h = (bhk >> 1) % NHEAD;
  const int tid = threadIdx.x, w = tid >> 6, lane = tid & 63, lr = lane & 15, lg = lane >> 4;

  const int e = eidx[bhk];
  const size_t eh = (size_t)e * NHEAD + h;
  short* H = hws + (size_t)bhk * HDIM * HIDD;

  const int e0 = eblk * 256 + w * 64;
  const int et0 = e0 >> 4;          // global e-tile base (16-wide tiles)
  const int ks0B = e0 >> 5;         // H-fragment ks base (32-wide)

  const short* W1Tp = wsb + OFF_W1T + (eh << 17);
  const short* Xp   = wsb + OFF_X + ((size_t)(bhk >> 1) << 14);
  const short* W1Cp = wsb + OFF_W1C + (eh << 12);
  const short* B1p  = wsb + OFF_B1 + (eh << 15);

  // MFMA1: T1[d][e] = sum_n X[d,n]*W1t[e,n];  A=X (m=d), B=W1t (n=e), k=n
  f32x4 acc1[4][4];  // [et][dt]
  #pragma unroll
  for (int et = 0; et < 4; ++et)
    #pragma unroll
    for (int dt = 0; dt < 4; ++dt) acc1[et][dt] = (f32x4){0.f, 0.f, 0.f, 0.f};
  #pragma unroll
  for (int ks = 0; ks < 8; ++ks) {
    bf16x8 wfr[4];
    #pragma unroll
    for (int et = 0; et < 4; ++et) {
      if (PP) wfr[et] = *(const bf16x8*)(W1Tp + (size_t)(((et0 + et) * 8 + ks) * 512) + lane * 8);
      else    wfr[et] = ld_gfrag(w1t + eh * HIDD * NTOK +
                                 (size_t)(e0 + et * 16 + lr) * NTOK + ks * 32 + lg * 8);
    }
    #pragma unroll
    for (int dt = 0; dt < 4; ++dt) {
      bf16x8 xfr;
      if (PP) xfr = *(const bf16x8*)(Xp + (size_t)((dt * 8 + ks) * 512) + lane * 8);
      else    xfr = ld_gfrag(x + (size_t)(bhk >> 1) * HDIM * NTOK +
                             (size_t)(dt * 16 + lr) * NTOK + ks * 32 + lg * 8);
      #pragma unroll
      for (int et = 0; et < 4; ++et) acc1[et][dt] = MFMA16(xfr, wfr[et], acc1[et][dt]);
    }
  }

  // relayout T1^T via wave-private LDS (col=e=lr, row=d=dt*16+lg*4+i) -> [e][d]
  char* t1 = smem + w * T1_W;
  #pragma unroll
  for (int et = 0; et < 4; ++et)
    #pragma unroll
    for (int dt = 0; dt < 4; ++dt) {
      bf16x4 p;
      #pragma unroll
      for (int i = 0; i < 4; ++i) p[i] = f2bf(acc1[et][dt][i]);
      *(bf16x4*)(t1 + (et * 16 + lr) * P_T1 + (dt * 16 + lg * 4) * 2) = p;
    }

  // MFMA2: T2^T[e][c] = sum_d T1^T[e,d]*W1c[c,d] + B1;  D: col=c=lr, row=e=lg*4+i
  f32x4 acc2[4][4];  // [et][ct]
  #pragma unroll
  for (int et = 0; et < 4; ++et)
    #pragma unroll
    for (int ct = 0; ct < 4; ++ct) {
      if (PP) {
        bf16x4 bb = *(const bf16x4*)(B1p + (size_t)((ct * 32 + et0 + et) * 256) + lane * 4);
        acc2[et][ct] = bf4f(bb);
      } else {
        acc2[et][ct] = *(const f32x4*)(b1 + eh * HDIM * HIDD +
                                       (size_t)(ct * 16 + lr) * HIDD + e0 + et * 16 + lg * 4);
      }
    }
  #pragma unroll
  for (int ks = 0; ks < 2; ++ks) {
    bf16x8 a[4];
    #pragma unroll
    for (int et = 0; et < 4; ++et)
      a[et] = *(const bf16x8*)(t1 + (et * 16 + lr) * P_T1 + (ks * 32 + lg * 8) * 2);
    #pragma unroll
    for (int ct = 0; ct < 4; ++ct) {
      bf16x8 bfr;
      if (PP) bfr = *(const bf16x8*)(W1Cp + (size_t)((ct * 2 + ks) * 512) + lane * 8);
      else    bfr = ld_gfrag(w1c + eh * HDIM * HDIM +
                             (size_t)(ct * 16 + lr) * HDIM + ks * 32 + lg * 8);
      #pragma unroll
      for (int et = 0; et < 4; ++et) acc2[et][ct] = MFMA16(a[et], bfr, acc2[et][ct]);
    }
  }

  // GELU + store H fragment-packed: H'[ct][ksB][lane][8]
  //   element (c=ct*16+lr, e=e0+et*16+lg*4+i): ksB=ks0B+(et>>1), lgB=(et&1)*2+(lg>>1)
  #pragma unroll
  for (int et = 0; et < 4; ++et) {
    const int ksB = ks0B + (et >> 1);
    const int lgB = (et & 1) * 2 + (lg >> 1);
    #pragma unroll
    for (int ct = 0; ct < 4; ++ct) {
      bf16x4 g;
      #pragma unroll
      for (int i = 0; i < 4; ++i) g[i] = f2bf(gelu_fast(acc2[et][ct][i]));
      if (PP) {
        *(bf16x4*)(H + (size_t)((ct * 16 + ksB) * 512) + (lgB * 16 + lr) * 8 + (lg & 1) * 4) = g;
      } else {
        *(bf16x4*)(H + (size_t)(ct * 16 + lr) * HIDD + e0 + et * 16 + lg * 4) = g;
      }
    }
  }
}

// ---------------- Kernel B v6 (64c x 64n per wave; fragment-packed loads) ----------------
// grid = 768 x 256. L = xcd_chunk(bx, 768): sid = L>>1 -> bh = order2[sid], nhalf = L&1.
// Wave w: kk = w>>1, wq = w&1; n rows [nhalf*128 + wq*64, +64). k=1 waves publish
// weighted partials via LDS (aliases dead t3), k=0 waves combine + plain f32 stores.
template <bool PP>
__global__ __launch_bounds__(256) void mixer_out_kernel(
    const int* __restrict__ eidx, const float* __restrict__ ewt,
    const float* __restrict__ w2t, const float* __restrict__ w2c, const float* __restrict__ b2,
    const short* __restrict__ wsb, const int* __restrict__ order2,
    const short* __restrict__ hws, float* __restrict__ out) {
  __shared__ __align__(16) char smem[SMB_TOTAL];
  const int L = xcd_chunk(blockIdx.x, NBH * 2);
  const int sid = L >> 1, nhalf = L & 1;
  const int bh = PP ? order2[sid] : sid;
  const int h = bh % NHEAD;
  const int tid = threadIdx.x, w = tid >> 6, lane = tid & 63, lr = lane & 15, lg = lane >> 4;
  const int kk = w >> 1, wq = w & 1;
  const int nb = nhalf * 128 + wq * 64;
  const int nt0 = nb >> 4;
  char* t3 = smem + w * T3_W;
  float* OUT = out + (size_t)bh * HDIM * NTOK;

  const int e = eidx[bh * TOPK + kk];
  const float wk = ewt[bh * TOPK + kk];
  const size_t eh = (size_t)e * NHEAD + h;
  const short* Hk = hws + (size_t)(bh * TOPK + kk) * HDIM * HIDD;
  const short* W2Tp = wsb + OFF_W2T + (eh << 17);
  const short* W2Cp = wsb + OFF_W2C + (eh << 12);
  const short* B2p  = wsb + OFF_B2 + (eh << 14);

  // MFMA3: T3[c][n] = sum_e H[c,e]*W2t[n,e];  A=H (m=c), B=W2t (n=n), k=e
  f32x4 acc3[4][4];  // [ct][nt]
  #pragma unroll
  for (int ct = 0; ct < 4; ++ct)
    #pragma unroll
    for (int nt = 0; nt < 4; ++nt) acc3[ct][nt] = (f32x4){0.f, 0.f, 0.f, 0.f};
  #pragma unroll 4
  for (int ks = 0; ks < 16; ++ks) {
    bf16x8 a[4];
    #pragma unroll
    for (int ct = 0; ct < 4; ++ct) {
      if (PP) a[ct] = *(const bf16x8*)(Hk + (size_t)((ct * 16 + ks) * 512) + lane * 8);
      else    a[ct] = *(const bf16x8*)(Hk + (size_t)(ct * 16 + lr) * HIDD + ks * 32 + lg * 8);
    }
    #pragma unroll
    for (int nt = 0; nt < 4; ++nt) {
      bf16x8 bfr;
      if (PP) bfr = *(const bf16x8*)(W2Tp + (size_t)(((nt0 + nt) * 16 + ks) * 512) + lane * 8);
      else    bfr = ld_gfrag(w2t + eh * NTOK * HIDD +
                             (size_t)(nb + nt * 16 + lr) * HIDD + ks * 32 + lg * 8);
      #pragma unroll
      for (int ct = 0; ct < 4; ++ct) acc3[ct][nt] = MFMA16(a[ct], bfr, acc3[ct][nt]);
    }
  }

  // relayout T3^T via wave-private LDS (col=n=lr, row=c=ct*16+lg*4+i) -> [n][c]
  #pragma unroll
  for (int ct = 0; ct < 4; ++ct)
    #pragma unroll
    for (int nt = 0; nt < 4; ++nt) {
      bf16x4 p;
      #pragma unroll
      for (int i = 0; i < 4; ++i) p[i] = f2bf(acc3[ct][nt][i]);
      *(bf16x4*)(t3 + (nt * 16 + lr) * P_T3 + (ct * 16 + lg * 4) * 2) = p;
    }

  // MFMA4: OUT^T[n][co] = sum_c T3^T[n,c]*W2c[co,c]
  f32x4 acc4[4][4];  // [nt][cot]
  #pragma unroll
  for (int nt = 0; nt < 4; ++nt)
    #pragma unroll
    for (int ct = 0; ct < 4; ++ct) acc4[nt][ct] = (f32x4){0.f, 0.f, 0.f, 0.f};
  #pragma unroll
  for (int ks = 0; ks < 2; ++ks) {
    bf16x8 a[4];
    #pragma unroll
    for (int nt = 0; nt < 4; ++nt)
      a[nt] = *(const bf16x8*)(t3 + (nt * 16 + lr) * P_T3 + (ks * 32 + lg * 8) * 2);
    #pragma unroll
    for (int ct = 0; ct < 4; ++ct) {
      bf16x8 bfr;
      if (PP) bfr = *(const bf16x8*)(W2Cp + (size_t)((ct * 2 + ks) * 512) + lane * 8);
      else    bfr = ld_gfrag(w2c + eh * HDIM * HDIM +
                             (size_t)(ct * 16 + lr) * HDIM + ks * 32 + lg * 8);
      #pragma unroll
      for (int nt = 0; nt < 4; ++nt) acc4[nt][ct] = MFMA16(a[nt], bfr, acc4[nt][ct]);
    }
  }

  // weighted partial in place: acc4 = wk*(acc4 + B2)  (col=co=lr, row=n=lg*4+i)
  #pragma unroll
  for (int nt = 0; nt < 4; ++nt)
    #pragma unroll
    for (int cot = 0; cot < 4; ++cot) {
      f32x4 bb;
      if (PP) bb = bf4f(*(const bf16x4*)(B2p + (size_t)((cot * 16 + nt0 + nt) * 256) + lane * 4));
      else    bb = *(const f32x4*)(b2 + eh * HDIM * NTOK +
                                   (size_t)(cot * 16 + lr) * NTOK + nb + nt * 16 + lg * 4);
      #pragma unroll
      for (int i = 0; i < 4; ++i) acc4[nt][cot][i] = wk * (acc4[nt][cot][i] + bb[i]);
    }

  __syncthreads();  // all waves done reading their t3 (comb aliases t3 region)

  // k=1 waves publish partials: comb[wq] = [64 n][64 co] f32 at offset wq*16384
  if (kk == 1) {
    float* comb = (float*)(smem + wq * 16384);
    #pragma unroll
    for (int nt = 0; nt < 4; ++nt)
      #pragma unroll
      for (int cot = 0; cot < 4; ++cot) {
        const int co = cot * 16 + lr;
        #pragma unroll
        for (int i = 0; i < 4; ++i)
          comb[(nt * 16 + lg * 4 + i) * 64 + co] = acc4[nt][cot][i];
      }
  }
  __syncthreads();

  // k=0 waves combine + store (each (co,n) written exactly once across the grid)
  if (kk == 0) {
    const float* comb = (const float*)(smem + wq * 16384);
    #pragma unroll
    for (int nt = 0; nt < 4; ++nt)
      #pragma unroll
      for (int cot = 0; cot < 4; ++cot) {
        const int co = cot * 16 + lr;
        const int n0 = nb + nt * 16 + lg * 4;
        f32x4 v;
        #pragma unroll
        for (int i = 0; i < 4; ++i)
          v[i] = acc4[nt][cot][i] + comb[(nt * 16 + lg * 4 + i) * 64 + co];
        *(f32x4*)(OUT + (size_t)co * NTOK + n0) = v;
      }
  }
}

extern "C" void kernel_launch(void* const* d_in, const int* in_sizes, int n_in,
                              void* d_out, int out_size, void* d_ws, size_t ws_size,
                              hipStream_t stream) {
  const float* x   = (const float*)d_in[0];
  const int*   ei  = (const int*)d_in[1];
  const float* ew  = (const float*)d_in[2];
  const float* w1t = (const float*)d_in[3];
  const float* w1c = (const float*)d_in[4];
  const float* b1  = (const float*)d_in[5];
  const float* w2t = (const float*)d_in[6];
  const float* w2c = (const float*)d_in[7];
  const float* b2  = (const float*)d_in[8];
  float* out = (float*)d_out;
  short* wsb = (short*)d_ws;
  short* hws = wsb + OFF_H;
  int* order  = (int*)(wsb + TOTEL);
  int* order2 = order + NCHAIN;

  if (ws_size >= NEED) {
    prepack_sort_kernel<<<dim3(NB_TOT / 4), dim3(256), 0, stream>>>(
        w1t, w2t, x, w1c, w2c, b1, b2, wsb, ei, order, order2);
    mixer_h_kernel<true><<<dim3(NCHAIN * 2), dim3(256), 0, stream>>>(
        x, ei, w1t, w1c, b1, wsb, order, hws);
    mixer_out_kernel<true><<<dim3(NBH * 2), dim3(256), 0, stream>>>(
        ei, ew, w2t, w2c, b2, wsb, order2, hws, out);
  } else {
    mixer_h_kernel<false><<<dim3(NCHAIN * 2), dim3(256), 0, stream>>>(
        x, ei, w1t, w1c, b1, wsb, order, hws);
    mixer_out_kernel<false><<<dim3(NBH * 2), dim3(256), 0, stream>>>(
        ei, ew, w2t, w2c, b2, wsb, order2, hws, out);
  }
}

// Round 23
// 130.868 us; speedup vs baseline: 1.0958x; 1.0958x over previous
//
#include <hip/hip_runtime.h>
#include <hip/hip_bf16.h>

// MultiHeadBatchedMixers, group-sorted two-kernel structure (no atomics):
//   prepack+sort (ASYNC gload_lds transpose): per 16-row band, stage-1 issues
//       global_load_lds DMA of the f32 band (LDS linear dest, PRE-SWIZZLED global
//       source: chunk ^= row&7 involution); barrier drains vmcnt; stage-2 reads
//       the same involution from LDS, converts f32->bf16, writes linear.
//   Kernel A (grid 1536x256, XCD-chunked, group-ordered): H = GELU(W1c@X@W1t^T+B1)
//   Kernel B (grid 768x256, XCD-chunked, group-ordered): 4 waves = 2k x 2wq,
//       64c x 64n per wave; LDS combine; plain f32 stores
// bf16 MFMA 16x16x32, f32 accumulate. Fragment-packed ws layout [tile][ks][lane][8].
// NOTE (R8/R10): VGPR+AGPR share one file; never min-waves-bound MFMA kernels.
// NOTE (R12-R14): cost tracks load instructions & intensity; 64x64 tiles optimal.
// NOTE (R15/R17): acc-lifetime splits and manual double-buffering are no-ops.
// NOTE (R18-R22): binding resource = memory segments/instr; prepack invariant at
// ~65us across 4 structures -> last hypothesis is the load->cvt->store chain,
// eliminated here via fire-and-forget global_load_lds DMA.

namespace {
constexpr int NHEAD = 12, NTOK = 256, HDIM = 64, HIDD = 512, NBATCH = 32, TOPK = 2;
constexpr int NCHAIN = NBATCH * NHEAD * TOPK;  // 768
constexpr int NBH = NBATCH * NHEAD;            // 384
constexpr int NGROUP = 8 * NHEAD;              // 96

// Kernel A LDS: per-wave T1^T [64 e][64 d] bf16, pitch +16B
constexpr int P_T1 = HDIM * 2 + 16;   // 144
constexpr int T1_W = 64 * P_T1;       // 9216
constexpr int SMA_TOTAL = 4 * T1_W;   // 36864
// Kernel B LDS: per-wave T3^T [64 n][64 c] (4 waves); combine aliases [0,32768)
constexpr int P_T3 = HDIM * 2 + 16;   // 144
constexpr int T3_W = 64 * P_T3;       // 9216
constexpr int SMB_TOTAL = 4 * T3_W;   // 36864

// ws element layout (bf16 shorts): [H][w1t][w2t][x][b1][b2][w1c][w2c], then orders
constexpr size_t SZ_H    = (size_t)NCHAIN * HDIM * HIDD;          // 25,165,824
constexpr size_t OFF_H   = 0;
constexpr size_t OFF_W1T = OFF_H + SZ_H;
constexpr size_t SZ_W1T  = (size_t)8 * NHEAD * HIDD * NTOK;       // 12,582,912
constexpr size_t OFF_W2T = OFF_W1T + SZ_W1T;
constexpr size_t SZ_W2T  = (size_t)8 * NHEAD * NTOK * HIDD;
constexpr size_t OFF_X   = OFF_W2T + SZ_W2T;
constexpr size_t SZ_X    = (size_t)NBATCH * NHEAD * HDIM * NTOK;  // 6,291,456
constexpr size_t OFF_B1  = OFF_X + SZ_X;
constexpr size_t SZ_B1   = (size_t)8 * NHEAD * HDIM * HIDD;
constexpr size_t OFF_B2  = OFF_B1 + SZ_B1;
constexpr size_t SZ_B2   = (size_t)8 * NHEAD * HDIM * NTOK;
constexpr size_t OFF_W1C = OFF_B2 + SZ_B2;
constexpr size_t SZ_W1C  = (size_t)8 * NHEAD * HDIM * HDIM;       // 393,216
constexpr size_t OFF_W2C = OFF_W1C + SZ_W1C;
constexpr size_t SZ_W2C  = (size_t)8 * NHEAD * HDIM * HDIM;
constexpr size_t TOTEL   = OFF_W2C + SZ_W2C;                      // shorts
constexpr size_t NEED    = TOTEL * 2 + (NCHAIN + NBH) * 4;

// prepack band counts (band = 16 rows x R cols, contiguous on both sides)
constexpr int NB_W1T = (int)(SZ_W1T / (16 * 256));  // 3072
constexpr int NB_W2T = (int)(SZ_W2T / (16 * 512));  // 1536
constexpr int NB_X   = (int)(SZ_X   / (16 * 256));  // 1536
constexpr int NB_W1C = (int)(SZ_W1C / (16 * 64));   // 384
constexpr int NB_W2C = (int)(SZ_W2C / (16 * 64));   // 384
constexpr int NB_B1  = (int)(SZ_B1  / (16 * 512));  // 384
constexpr int NB_B2  = (int)(SZ_B2  / (16 * 256));  // 384
constexpr int NB_TOT = NB_W1T + NB_W2T + NB_X + NB_W1C + NB_W2C + NB_B1 + NB_B2;  // 7680
}

typedef float f32x4 __attribute__((ext_vector_type(4)));
typedef short bf16x8 __attribute__((ext_vector_type(8)));
typedef short bf16x4 __attribute__((ext_vector_type(4)));

#define MFMA16(a, b, c) __builtin_amdgcn_mfma_f32_16x16x32_bf16((a), (b), (c), 0, 0, 0)

#define GLOAD_LDS16(g, l)                                                  \
  __builtin_amdgcn_global_load_lds(                                        \
      (const __attribute__((address_space(1))) unsigned int*)(g),          \
      (__attribute__((address_space(3))) unsigned int*)(l), 16, 0, 0)

__device__ __forceinline__ short f2bf(float f) {
  union { float f; unsigned u; } v; v.f = f;
  unsigned r = v.u + 0x7fffu + ((v.u >> 16) & 1u);
  return (short)(r >> 16);
}

__device__ __forceinline__ bf16x8 ld_gfrag(const float* p) {
  float4 a = *(const float4*)p;
  float4 b = *(const float4*)(p + 4);
  bf16x8 r;
  r[0] = f2bf(a.x); r[1] = f2bf(a.y); r[2] = f2bf(a.z); r[3] = f2bf(a.w);
  r[4] = f2bf(b.x); r[5] = f2bf(b.y); r[6] = f2bf(b.z); r[7] = f2bf(b.w);
  return r;
}

__device__ __forceinline__ f32x4 bf4f(bf16x4 v) {
  f32x4 r;
  #pragma unroll
  for (int i = 0; i < 4; ++i) {
    union { unsigned u; float f; } t;
    t.u = ((unsigned)(unsigned short)v[i]) << 16;
    r[i] = t.f;
  }
  return r;
}

// gelu(x) = x * rcp(1 + exp2(-2.30220826 * x * (1 + 0.044715 x^2)))  [err ~1e-7 << bf16]
__device__ __forceinline__ float gelu_fast(float x) {
  float arg = -2.30220826f * x * __builtin_fmaf(0.044715f, x * x, 1.0f);
  float e = __builtin_amdgcn_exp2f(arg);
  return x * __builtin_amdgcn_rcpf(1.0f + e);
}

// XCD-chunk swizzle (nwg % 8 == 0): logical sequence contiguous per XCD.
__device__ __forceinline__ int xcd_chunk(int bx, int nwg) {
  return (bx & 7) * (nwg >> 3) + (bx >> 3);
}

// bias-path LDS swizzle (8B chunks, self-inverse)
__device__ __forceinline__ int swz8(int c)  { return c ^ (((c >> 4) & 3) << 1); }

// ---------------- Prepack (+ block-0 group sort), async gload_lds transpose ----------------
__global__ __launch_bounds__(256) void prepack_sort_kernel(
    const float* __restrict__ w1t, const float* __restrict__ w2t,
    const float* __restrict__ x, const float* __restrict__ w1c,
    const float* __restrict__ w2c, const float* __restrict__ b1,
    const float* __restrict__ b2, short* __restrict__ wsb,
    const int* __restrict__ eidx, int* __restrict__ order, int* __restrict__ order2) {
  if (blockIdx.x == 0) {
    __shared__ int keys[NCHAIN];
    __shared__ int keys2[NBH];
    __shared__ int cnt[NGROUP + 1];
    __shared__ int cnt2[NGROUP + 1];
    const int t = threadIdx.x;
    for (int i = t; i <= NGROUP; i += 256) { cnt[i] = 0; cnt2[i] = 0; }
    __syncthreads();
    for (int i = t; i < NCHAIN; i += 256) {
      int h = (i >> 1) % NHEAD;
      int key = eidx[i] * NHEAD + h;
      keys[i] = key;
      atomicAdd(&cnt[key + 1], 1);
    }
    for (int i = t; i < NBH; i += 256) {
      int h = i % NHEAD;
      int key = eidx[i * TOPK] * NHEAD + h;
      keys2[i] = key;
      atomicAdd(&cnt2[key + 1], 1);
    }
    __syncthreads();
    if (t == 0) for (int i = 1; i <= NGROUP; ++i) cnt[i] += cnt[i - 1];
    if (t == 1) for (int i = 1; i <= NGROUP; ++i) cnt2[i] += cnt2[i - 1];
    __syncthreads();
    for (int i = t; i < NCHAIN; i += 256) {
      int pos = atomicAdd(&cnt[keys[i]], 1);  // rank within group (order-agnostic downstream)
      order[pos] = i;
    }
    for (int i = t; i < NBH; i += 256) {
      int pos = atomicAdd(&cnt2[keys2[i]], 1);
      order2[pos] = i;
    }
    __syncthreads();
  }

  __shared__ __align__(16) float tilef[8192];     // 32KB: one band of f32 (max 16x512)
  short* tile = (short*)tilef;                    // bias path view (bf16)

  const int w64 = (threadIdx.x >> 6) * 64;        // wave base lane-chunk
  const int lane = threadIdx.x & 63;

  for (int band = blockIdx.x; band < NB_TOT; band += gridDim.x) {
    const float* s; size_t dbase; int R, rcSh, tprSh; bool g8;
    int bb = band;
    if (bb < NB_W1T)                 { s = w1t; dbase = OFF_W1T; R = 256; rcSh = 6; tprSh = 3; g8 = true; }
    else if ((bb -= NB_W1T) < NB_W2T){ s = w2t; dbase = OFF_W2T; R = 512; rcSh = 7; tprSh = 4; g8 = true; }
    else if ((bb -= NB_W2T) < NB_X)  { s = x;   dbase = OFF_X;   R = 256; rcSh = 6; tprSh = 3; g8 = true; }
    else if ((bb -= NB_X) < NB_W1C)  { s = w1c; dbase = OFF_W1C; R = 64;  rcSh = 4; tprSh = 1; g8 = true; }
    else if ((bb -= NB_W1C) < NB_W2C){ s = w2c; dbase = OFF_W2C; R = 64;  rcSh = 4; tprSh = 1; g8 = true; }
    else if ((bb -= NB_W2C) < NB_B1) { s = b1;  dbase = OFF_B1;  R = 512; rcSh = 7; tprSh = 5; g8 = false; }
    else                             { bb -= NB_B1; s = b2; dbase = OFF_B2; R = 256; rcSh = 6; tprSh = 4; g8 = false; }

    const size_t eloff = (size_t)bb * 16 * R;

    if (g8) {
      // stage 1: async DMA band f32 -> LDS (linear dest, source chunk ^= row&7)
      const int nc = 4 * R;  // 16B chunks in band (multiple of 256)
      const float* bs = s + eloff;
      for (int c0 = w64; c0 < nc; c0 += 256) {
        const int c = c0 + lane;
        const int row = c >> rcSh, cir = c & ((1 << rcSh) - 1);
        const float* g = bs + (((size_t)row << rcSh) + (cir ^ (row & 7))) * 4;
        GLOAD_LDS16(g, tilef + (size_t)c0 * 4);
      }
      __syncthreads();  // drains vmcnt for gload_lds

      // stage 2: swizzled LDS read (f32) + convert + linear global write (bf16)
      const int n8 = (16 * R) / 8;
      for (int l8 = threadIdx.x; l8 < n8; l8 += 256) {
        const int frag = l8 >> 6, l6 = l8 & 63;
        const int c8 = ((frag & ((1 << tprSh) - 1)) << 2) + (l6 >> 4);
        const int r  = ((frag >> tprSh) << 4) + (l6 & 15);
        const int ch0 = (r << rcSh) + ((2 * c8) ^ (r & 7));
        const int ch1 = (r << rcSh) + ((2 * c8 + 1) ^ (r & 7));
        f32x4 a = *(const f32x4*)(tilef + ch0 * 4);
        f32x4 b = *(const f32x4*)(tilef + ch1 * 4);
        bf16x8 v;
        #pragma unroll
        for (int i = 0; i < 4; ++i) { v[i] = f2bf(a[i]); v[4 + i] = f2bf(b[i]); }
        *(bf16x8*)(wsb + dbase + eloff + (size_t)l8 * 8) = v;
      }
    } else {
      // bias path (R21): VGPR read + convert + swizzled bf16 LDS, then linear out
      const int n8 = (16 * R) / 8;
      for (int l8 = threadIdx.x; l8 < n8; l8 += 256) {
        const int l = l8 * 8;
        const int r = l >> rcSh >> 2, c = l & (R - 1);  // l/R, l%R (R=1<<(rcSh+2))
        bf16x8 v = ld_gfrag(s + eloff + l);
        #pragma unroll
        for (int q = 0; q < 2; ++q) {
          const int e4 = (c >> 2) + q;
          const int chunk = (e4 >> 2) * 64 + (e4 & 3) * 16 + r;
          bf16x4 p;
          #pragma unroll
          for (int i = 0; i < 4; ++i) p[i] = v[q * 4 + i];
          *(bf16x4*)(tile + swz8(chunk) * 4) = p;
        }
      }
      __syncthreads();
      for (int l8 = threadIdx.x; l8 < n8; l8 += 256) {
        const int l4 = l8 * 2;
        bf16x8 v;
        bf16x4 a = *(const bf16x4*)(tile + swz8(l4) * 4);
        bf16x4 b = *(const bf16x4*)(tile + swz8(l4 + 1) * 4);
        #pragma unroll
        for (int i = 0; i < 4; ++i) { v[i] = a[i]; v[4 + i] = b[i]; }
        *(bf16x8*)(wsb + dbase + eloff + (size_t)l8 * 8) = v;
      }
    }
    __syncthreads();  // protect tile before next band
  }
}

// ---------------- Kernel A (64 e per wave; fragment-packed loads/stores) ----------------
// grid = 768*2. L = xcd_chunk(bx,1536): sid = L>>1 -> chain = order[sid], eblk = L&1.
template <bool PP>
__global__ __launch_bounds__(256) void mixer_h_kernel(
    const float* __restrict__ x, const int* __restrict__ eidx,
    const float* __restrict__ w1t, const float* __restrict__ w1c, const float* __restrict__ b1,
    const short* __restrict__ wsb, const int* __restrict__ order, short* __restrict__ hws) {
  __shared__ __align__(16) char smem[SMA_TOTAL];
  const int L = xcd_chunk(blockIdx.x, NCHAIN * 2);
  const int sid = L >> 1, eblk = L & 1;
  const int bhk = PP ? order[sid] : sid;
  const int h = (bhk >> 1) % NHEAD;
  const int tid = threadIdx.x, w = tid >> 6, lane = tid & 63, lr = lane & 15, lg = lane >> 4;

  const int e = eidx[bhk];
  const size_t eh = (size_t)e * NHEAD + h;
  short* H = hws + (size_t)bhk * HDIM * HIDD;

  const int e0 = eblk * 256 + w * 64;
  const int et0 = e0 >> 4;          // global e-tile base (16-wide tiles)
  const int ks0B = e0 >> 5;         // H-fragment ks base (32-wide)

  const short* W1Tp = wsb + OFF_W1T + (eh << 17);
  const short* Xp   = wsb + OFF_X + ((size_t)(bhk >> 1) << 14);
  const short* W1Cp = wsb + OFF_W1C + (eh << 12);
  const short* B1p  = wsb + OFF_B1 + (eh << 15);

  // MFMA1: T1[d][e] = sum_n X[d,n]*W1t[e,n];  A=X (m=d), B=W1t (n=e), k=n
  f32x4 acc1[4][4];  // [et][dt]
  #pragma unroll
  for (int et = 0; et < 4; ++et)
    #pragma unroll
    for (int dt = 0; dt < 4; ++dt) acc1[et][dt] = (f32x4){0.f, 0.f, 0.f, 0.f};
  #pragma unroll
  for (int ks = 0; ks < 8; ++ks) {
    bf16x8 wfr[4];
    #pragma unroll
    for (int et = 0; et < 4; ++et) {
      if (PP) wfr[et] = *(const bf16x8*)(W1Tp + (size_t)(((et0 + et) * 8 + ks) * 512) + lane * 8);
      else    wfr[et] = ld_gfrag(w1t + eh * HIDD * NTOK +
                                 (size_t)(e0 + et * 16 + lr) * NTOK + ks * 32 + lg * 8);
    }
    #pragma unroll
    for (int dt = 0; dt < 4; ++dt) {
      bf16x8 xfr;
      if (PP) xfr = *(const bf16x8*)(Xp + (size_t)((dt * 8 + ks) * 512) + lane * 8);
      else    xfr = ld_gfrag(x + (size_t)(bhk >> 1) * HDIM * NTOK +
                             (size_t)(dt * 16 + lr) * NTOK + ks * 32 + lg * 8);
      #pragma unroll
      for (int et = 0; et < 4; ++et) acc1[et][dt] = MFMA16(xfr, wfr[et], acc1[et][dt]);
    }
  }

  // relayout T1^T via wave-private LDS (col=e=lr, row=d=dt*16+lg*4+i) -> [e][d]
  char* t1 = smem + w * T1_W;
  #pragma unroll
  for (int et = 0; et < 4; ++et)
    #pragma unroll
    for (int dt = 0; dt < 4; ++dt) {
      bf16x4 p;
      #pragma unroll
      for (int i = 0; i < 4; ++i) p[i] = f2bf(acc1[et][dt][i]);
      *(bf16x4*)(t1 + (et * 16 + lr) * P_T1 + (dt * 16 + lg * 4) * 2) = p;
    }

  // MFMA2: T2^T[e][c] = sum_d T1^T[e,d]*W1c[c,d] + B1;  D: col=c=lr, row=e=lg*4+i
  f32x4 acc2[4][4];  // [et][ct]
  #pragma unroll
  for (int et = 0; et < 4; ++et)
    #pragma unroll
    for (int ct = 0; ct < 4; ++ct) {
      if (PP) {
        bf16x4 bb = *(const bf16x4*)(B1p + (size_t)((ct * 32 + et0 + et) * 256) + lane * 4);
        acc2[et][ct] = bf4f(bb);
      } else {
        acc2[et][ct] = *(const f32x4*)(b1 + eh * HDIM * HIDD +
                                       (size_t)(ct * 16 + lr) * HIDD + e0 + et * 16 + lg * 4);
      }
    }
  #pragma unroll
  for (int ks = 0; ks < 2; ++ks) {
    bf16x8 a[4];
    #pragma unroll
    for (int et = 0; et < 4; ++et)
      a[et] = *(const bf16x8*)(t1 + (et * 16 + lr) * P_T1 + (ks * 32 + lg * 8) * 2);
    #pragma unroll
    for (int ct = 0; ct < 4; ++ct) {
      bf16x8 bfr;
      if (PP) bfr = *(const bf16x8*)(W1Cp + (size_t)((ct * 2 + ks) * 512) + lane * 8);
      else    bfr = ld_gfrag(w1c + eh * HDIM * HDIM +
                             (size_t)(ct * 16 + lr) * HDIM + ks * 32 + lg * 8);
      #pragma unroll
      for (int et = 0; et < 4; ++et) acc2[et][ct] = MFMA16(a[et], bfr, acc2[et][ct]);
    }
  }

  // GELU + store H fragment-packed: H'[ct][ksB][lane][8]
  //   element (c=ct*16+lr, e=e0+et*16+lg*4+i): ksB=ks0B+(et>>1), lgB=(et&1)*2+(lg>>1)
  #pragma unroll
  for (int et = 0; et < 4; ++et) {
    const int ksB = ks0B + (et >> 1);
    const int lgB = (et & 1) * 2 + (lg >> 1);
    #pragma unroll
    for (int ct = 0; ct < 4; ++ct) {
      bf16x4 g;
      #pragma unroll
      for (int i = 0; i < 4; ++i) g[i] = f2bf(gelu_fast(acc2[et][ct][i]));
      if (PP) {
        *(bf16x4*)(H + (size_t)((ct * 16 + ksB) * 512) + (lgB * 16 + lr) * 8 + (lg & 1) * 4) = g;
      } else {
        *(bf16x4*)(H + (size_t)(ct * 16 + lr) * HIDD + e0 + et * 16 + lg * 4) = g;
      }
    }
  }
}

// ---------------- Kernel B v6 (64c x 64n per wave; fragment-packed loads) ----------------
// grid = 768 x 256. L = xcd_chunk(bx, 768): sid = L>>1 -> bh = order2[sid], nhalf = L&1.
// Wave w: kk = w>>1, wq = w&1; n rows [nhalf*128 + wq*64, +64). k=1 waves publish
// weighted partials via LDS (aliases dead t3), k=0 waves combine + plain f32 stores.
template <bool PP>
__global__ __launch_bounds__(256) void mixer_out_kernel(
    const int* __restrict__ eidx, const float* __restrict__ ewt,
    const float* __restrict__ w2t, const float* __restrict__ w2c, const float* __restrict__ b2,
    const short* __restrict__ wsb, const int* __restrict__ order2,
    const short* __restrict__ hws, float* __restrict__ out) {
  __shared__ __align__(16) char smem[SMB_TOTAL];
  const int L = xcd_chunk(blockIdx.x, NBH * 2);
  const int sid = L >> 1, nhalf = L & 1;
  const int bh = PP ? order2[sid] : sid;
  const int h = bh % NHEAD;
  const int tid = threadIdx.x, w = tid >> 6, lane = tid & 63, lr = lane & 15, lg = lane >> 4;
  const int kk = w >> 1, wq = w & 1;
  const int nb = nhalf * 128 + wq * 64;
  const int nt0 = nb >> 4;
  char* t3 = smem + w * T3_W;
  float* OUT = out + (size_t)bh * HDIM * NTOK;

  const int e = eidx[bh * TOPK + kk];
  const float wk = ewt[bh * TOPK + kk];
  const size_t eh = (size_t)e * NHEAD + h;
  const short* Hk = hws + (size_t)(bh * TOPK + kk) * HDIM * HIDD;
  const short* W2Tp = wsb + OFF_W2T + (eh << 17);
  const short* W2Cp = wsb + OFF_W2C + (eh << 12);
  const short* B2p  = wsb + OFF_B2 + (eh << 14);

  // MFMA3: T3[c][n] = sum_e H[c,e]*W2t[n,e];  A=H (m=c), B=W2t (n=n), k=e
  f32x4 acc3[4][4];  // [ct][nt]
  #pragma unroll
  for (int ct = 0; ct < 4; ++ct)
    #pragma unroll
    for (int nt = 0; nt < 4; ++nt) acc3[ct][nt] = (f32x4){0.f, 0.f, 0.f, 0.f};
  #pragma unroll 4
  for (int ks = 0; ks < 16; ++ks) {
    bf16x8 a[4];
    #pragma unroll
    for (int ct = 0; ct < 4; ++ct) {
      if (PP) a[ct] = *(const bf16x8*)(Hk + (size_t)((ct * 16 + ks) * 512) + lane * 8);
      else    a[ct] = *(const bf16x8*)(Hk + (size_t)(ct * 16 + lr) * HIDD + ks * 32 + lg * 8);
    }
    #pragma unroll
    for (int nt = 0; nt < 4; ++nt) {
      bf16x8 bfr;
      if (PP) bfr = *(const bf16x8*)(W2Tp + (size_t)(((nt0 + nt) * 16 + ks) * 512) + lane * 8);
      else    bfr = ld_gfrag(w2t + eh * NTOK * HIDD +
                             (size_t)(nb + nt * 16 + lr) * HIDD + ks * 32 + lg * 8);
      #pragma unroll
      for (int ct = 0; ct < 4; ++ct) acc3[ct][nt] = MFMA16(a[ct], bfr, acc3[ct][nt]);
    }
  }

  // relayout T3^T via wave-private LDS (col=n=lr, row=c=ct*16+lg*4+i) -> [n][c]
  #pragma unroll
  for (int ct = 0; ct < 4; ++ct)
    #pragma unroll
    for (int nt = 0; nt < 4; ++nt) {
      bf16x4 p;
      #pragma unroll
      for (int i = 0; i < 4; ++i) p[i] = f2bf(acc3[ct][nt][i]);
      *(bf16x4*)(t3 + (nt * 16 + lr) * P_T3 + (ct * 16 + lg * 4) * 2) = p;
    }

  // MFMA4: OUT^T[n][co] = sum_c T3^T[n,c]*W2c[co,c]
  f32x4 acc4[4][4];  // [nt][cot]
  #pragma unroll
  for (int nt = 0; nt < 4; ++nt)
    #pragma unroll
    for (int ct = 0; ct < 4; ++ct) acc4[nt][ct] = (f32x4){0.f, 0.f, 0.f, 0.f};
  #pragma unroll
  for (int ks = 0; ks < 2; ++ks) {
    bf16x8 a[4];
    #pragma unroll
    for (int nt = 0; nt < 4; ++nt)
      a[nt] = *(const bf16x8*)(t3 + (nt * 16 + lr) * P_T3 + (ks * 32 + lg * 8) * 2);
    #pragma unroll
    for (int ct = 0; ct < 4; ++ct) {
      bf16x8 bfr;
      if (PP) bfr = *(const bf16x8*)(W2Cp + (size_t)((ct * 2 + ks) * 512) + lane * 8);
      else    bfr = ld_gfrag(w2c + eh * HDIM * HDIM +
                             (size_t)(ct * 16 + lr) * HDIM + ks * 32 + lg * 8);
      #pragma unroll
      for (int nt = 0; nt < 4; ++nt) acc4[nt][ct] = MFMA16(a[nt], bfr, acc4[nt][ct]);
    }
  }

  // weighted partial in place: acc4 = wk*(acc4 + B2)  (col=co=lr, row=n=lg*4+i)
  #pragma unroll
  for (int nt = 0; nt < 4; ++nt)
    #pragma unroll
    for (int cot = 0; cot < 4; ++cot) {
      f32x4 bb;
      if (PP) bb = bf4f(*(const bf16x4*)(B2p + (size_t)((cot * 16 + nt0 + nt) * 256) + lane * 4));
      else    bb = *(const f32x4*)(b2 + eh * HDIM * NTOK +
                                   (size_t)(cot * 16 + lr) * NTOK + nb + nt * 16 + lg * 4);
      #pragma unroll
      for (int i = 0; i < 4; ++i) acc4[nt][cot][i] = wk * (acc4[nt][cot][i] + bb[i]);
    }

  __syncthreads();  // all waves done reading their t3 (comb aliases t3 region)

  // k=1 waves publish partials: comb[wq] = [64 n][64 co] f32 at offset wq*16384
  if (kk == 1) {
    float* comb = (float*)(smem + wq * 16384);
    #pragma unroll
    for (int nt = 0; nt < 4; ++nt)
      #pragma unroll
      for (int cot = 0; cot < 4; ++cot) {
        const int co = cot * 16 + lr;
        #pragma unroll
        for (int i = 0; i < 4; ++i)
          comb[(nt * 16 + lg * 4 + i) * 64 + co] = acc4[nt][cot][i];
      }
  }
  __syncthreads();

  // k=0 waves combine + store (each (co,n) written exactly once across the grid)
  if (kk == 0) {
    const float* comb = (const float*)(smem + wq * 16384);
    #pragma unroll
    for (int nt = 0; nt < 4; ++nt)
      #pragma unroll
      for (int cot = 0; cot < 4; ++cot) {
        const int co = cot * 16 + lr;
        const int n0 = nb + nt * 16 + lg * 4;
        f32x4 v;
        #pragma unroll
        for (int i = 0; i < 4; ++i)
          v[i] = acc4[nt][cot][i] + comb[(nt * 16 + lg * 4 + i) * 64 + co];
        *(f32x4*)(OUT + (size_t)co * NTOK + n0) = v;
      }
  }
}

extern "C" void kernel_launch(void* const* d_in, const int* in_sizes, int n_in,
                              void* d_out, int out_size, void* d_ws, size_t ws_size,
                              hipStream_t stream) {
  const float* x   = (const float*)d_in[0];
  const int*   ei  = (const int*)d_in[1];
  const float* ew  = (const float*)d_in[2];
  const float* w1t = (const float*)d_in[3];
  const float* w1c = (const float*)d_in[4];
  const float* b1  = (const float*)d_in[5];
  const float* w2t = (const float*)d_in[6];
  const float* w2c = (const float*)d_in[7];
  const float* b2  = (const float*)d_in[8];
  float* out = (float*)d_out;
  short* wsb = (short*)d_ws;
  short* hws = wsb + OFF_H;
  int* order  = (int*)(wsb + TOTEL);
  int* order2 = order + NCHAIN;

  if (ws_size >= NEED) {
    prepack_sort_kernel<<<dim3(2048), dim3(256), 0, stream>>>(
        w1t, w2t, x, w1c, w2c, b1, b2, wsb, ei, order, order2);
    mixer_h_kernel<true><<<dim3(NCHAIN * 2), dim3(256), 0, stream>>>(
        x, ei, w1t, w1c, b1, wsb, order, hws);
    mixer_out_kernel<true><<<dim3(NBH * 2), dim3(256), 0, stream>>>(
        ei, ew, w2t, w2c, b2, wsb, order2, hws, out);
  } else {
    mixer_h_kernel<false><<<dim3(NCHAIN * 2), dim3(256), 0, stream>>>(
        x, ei, w1t, w1c, b1, wsb, order, hws);
    mixer_out_kernel<false><<<dim3(NBH * 2), dim3(256), 0, stream>>>(
        ei, ew, w2t, w2c, b2, wsb, order2, hws, out);
  }
}